// Round 1
// baseline (343.191 us; speedup 1.0000x reference)
//
#include <hip/hip_runtime.h>

// Problem: per-batch segment_sum over sorted segment ids.
// B=16, L=4096, H=768, fp32. out[b,j,:] = sum_{p: seg[b,p]==j} x[b,p,:].
// Sorted ids => token j's wordpieces are the contiguous range
// [lower_bound(seg_b, j), lower_bound(seg_b, j+1)).
#define BB 16
#define LL 4096
#define H4 192    // 768 floats = 192 float4 per row
#define SP 4104   // starts row stride (needs LL+1 entries; padded)

typedef float nf4 __attribute__((ext_vector_type(4)));

// ---------------------------------------------------------------------------
// Kernel A: precompute starts[b][j] = lower_bound(seg_b, j) for j in [0, LL].
// Thread handles one wordpiece position p. Positions partition [0, LL] into
// runs (seg[p-1], seg[p]] -> lb = p (with seg[-1] := -1), plus the tail
// (seg[LL-1], LL] -> lb = LL. Every entry written every call (poison-safe).
// ---------------------------------------------------------------------------
__global__ __launch_bounds__(256) void bounds_kernel(
    const int* __restrict__ seg, int* __restrict__ starts) {
    int b = blockIdx.x >> 4;                       // 16 blocks per batch row
    int p = ((blockIdx.x & 15) << 8) | threadIdx.x;
    const int* __restrict__ sb = seg + (b << 12);
    int* __restrict__ st = starts + b * SP;

    int cur  = sb[p];
    int prev = (p == 0) ? -1 : sb[p - 1];
    for (int j = prev + 1; j <= cur; ++j) st[j] = p;
    if (p == LL - 1)
        for (int j = cur + 1; j <= LL; ++j) st[j] = LL;
}

// ---------------------------------------------------------------------------
// Kernel B: one wave per output token (b, j). Reads its [s, e) range from the
// precomputed table (2 uniform-address dword loads, L2-hit), gather-sums
// float4 columns {lane, lane+64, lane+128} over rows [s, e), and writes the
// output row with non-temporal stores (out is write-once; keep x in L3).
// ---------------------------------------------------------------------------
__global__ __launch_bounds__(256) void segsum_bounds_kernel(
    const float4* __restrict__ x, const int* __restrict__ starts,
    float4* __restrict__ out) {
    int gtid = blockIdx.x * blockDim.x + threadIdx.x;
    int wave = gtid >> 6;          // 0 .. B*L-1
    int lane = gtid & 63;
    int b = wave >> 12;            // / L
    int j = wave & (LL - 1);       // % L

    const int* __restrict__ st = starts + b * SP + j;
    int s = st[0];                 // lb(j)
    int e = st[1];                 // lb(j+1)

    float4 a0 = make_float4(0.f, 0.f, 0.f, 0.f);
    float4 a1 = a0, a2 = a0;

    const float4* xb = x + (size_t)b * LL * H4;
    for (int p = s; p < e; ++p) {
        const float4* row = xb + (size_t)p * H4 + lane;
        float4 v0 = row[0];
        float4 vA = row[64];
        float4 vB = row[128];
        a0.x += v0.x; a0.y += v0.y; a0.z += v0.z; a0.w += v0.w;
        a1.x += vA.x; a1.y += vA.y; a1.z += vA.z; a1.w += vA.w;
        a2.x += vB.x; a2.y += vB.y; a2.z += vB.z; a2.w += vB.w;
    }

    nf4* orow = (nf4*)(out + (size_t)wave * H4 + lane);
    nf4 n0 = {a0.x, a0.y, a0.z, a0.w};
    nf4 n1 = {a1.x, a1.y, a1.z, a1.w};
    nf4 n2 = {a2.x, a2.y, a2.z, a2.w};
    __builtin_nontemporal_store(n0, orow);
    __builtin_nontemporal_store(n1, orow + 64);
    __builtin_nontemporal_store(n2, orow + 128);
}

// ---------------------------------------------------------------------------
// Fallback: previous fused kernel (in-wave 64-ary ballot search) in case the
// workspace is unavailable/too small. Known-good at ~86 us.
// ---------------------------------------------------------------------------
__global__ __launch_bounds__(256) void segsum_fused_kernel(
    const float4* __restrict__ x, const int* __restrict__ seg,
    float4* __restrict__ out) {
    int gtid = blockIdx.x * blockDim.x + threadIdx.x;
    int wave = gtid >> 6;
    int lane = gtid & 63;
    int b = wave >> 12;
    int j = wave & (LL - 1);

    const int* __restrict__ sb = seg + ((size_t)b << 12);

    int v1 = sb[lane << 6];
    unsigned long long ms = __ballot(v1 >= j);
    unsigned long long me = __ballot(v1 > j);

    int s, e;
    if (ms & 1ull) {
        s = 0;
    } else {
        int f = ms ? (__ffsll((unsigned long long)ms) - 1) : 64;
        int base = ((f - 1) << 6) + 1;
        int p2 = base + lane;
        int v2 = (p2 < LL) ? sb[p2] : 0x7fffffff;
        unsigned long long m2 = __ballot(v2 >= j);
        s = base + __ffsll(m2) - 1;
    }
    if (me & 1ull) {
        e = 0;
    } else {
        int f = me ? (__ffsll((unsigned long long)me) - 1) : 64;
        int base = ((f - 1) << 6) + 1;
        int p2 = base + lane;
        int v2 = (p2 < LL) ? sb[p2] : 0x7fffffff;
        unsigned long long m2 = __ballot(v2 > j);
        e = base + __ffsll(m2) - 1;
    }

    float4 a0 = make_float4(0.f, 0.f, 0.f, 0.f);
    float4 a1 = a0, a2 = a0;

    const float4* xb = x + (size_t)b * LL * H4;
    for (int p = s; p < e; ++p) {
        const float4* row = xb + (size_t)p * H4 + lane;
        float4 v0 = row[0];
        float4 vA = row[64];
        float4 vB = row[128];
        a0.x += v0.x; a0.y += v0.y; a0.z += v0.z; a0.w += v0.w;
        a1.x += vA.x; a1.y += vA.y; a1.z += vA.z; a1.w += vA.w;
        a2.x += vB.x; a2.y += vB.y; a2.z += vB.z; a2.w += vB.w;
    }

    float4* orow = out + (size_t)wave * H4 + lane;
    orow[0]   = a0;
    orow[64]  = a1;
    orow[128] = a2;
}

extern "C" void kernel_launch(void* const* d_in, const int* in_sizes, int n_in,
                              void* d_out, int out_size, void* d_ws, size_t ws_size,
                              hipStream_t stream) {
    const float* x   = (const float*)d_in[0];   // (B, L, H) fp32
    const int*   seg = (const int*)d_in[1];     // (B, L) int32, sorted per row
    float* out = (float*)d_out;                 // (B, L, H) fp32

    size_t need = (size_t)BB * SP * sizeof(int);   // 262 KB bound table
    if (d_ws != nullptr && ws_size >= need) {
        int* starts = (int*)d_ws;
        // Kernel A: 16 blocks per batch row, one thread per wordpiece.
        bounds_kernel<<<BB * 16, 256, 0, stream>>>(seg, starts);
        // Kernel B: B*L waves, 4 waves per 256-thread block.
        segsum_bounds_kernel<<<(BB * LL) / 4, 256, 0, stream>>>(
            (const float4*)x, starts, (float4*)out);
    } else {
        segsum_fused_kernel<<<(BB * LL) / 4, 256, 0, stream>>>(
            (const float4*)x, seg, (float4*)out);
    }
}